// Round 8
// baseline (47.128 us; speedup 1.0000x reference)
//
#include <hip/hip_runtime.h>

#define Bn 4
#define Sn 512
#define Hn 128
#define ST 4   // s-rows per softpv block

__device__ __forceinline__ float fast_exp2(float x) { return __builtin_amdgcn_exp2f(x); }
__device__ __forceinline__ float fast_rcp(float x)  { return __builtin_amdgcn_rcpf(x); }

#define C2 2.8853900817779268f   // 2*log2(e)

// Kernel 1: eq[b][s][h] = exp2(C2*(q@Wq^T + bias)) ; ekT[b][h][t] = exp2(C2*(k@Wk^T))
__global__ __launch_bounds__(256) void proj_kernel(
    const float* __restrict__ query, const float* __restrict__ key,
    const float* __restrict__ attn_W, const float* __restrict__ attn_b,
    float* __restrict__ eq, float* __restrict__ ekT)
{
    __shared__ float rows[2][4][Hn];       // 4 KB
    const int row0 = blockIdx.x * 4;       // global (b*S+s) row
    const int b    = row0 / Sn;
    const int t0   = row0 % Sn;            // multiple of 4
    const int tid  = threadIdx.x;

    {   // 2*4*128 floats = 256 float4, one per thread
        int src = tid >> 7, r = (tid >> 5) & 3, c4 = tid & 31;
        ((float4*)rows)[tid] =
            reinterpret_cast<const float4*>(src ? key : query)[(row0 + r) * 32 + c4];
    }
    __syncthreads();

    const int o     = tid & 127;
    const int which = tid >> 7;            // 0 = q-proj, 1 = k-proj (wave-uniform)
    float acc[4] = {0,0,0,0};
    const float* wrow = attn_W + o * (2 * Hn) + which * Hn;
    for (int c = 0; c < Hn; c += 4) {
        float4 wv = *reinterpret_cast<const float4*>(wrow + c);
        #pragma unroll
        for (int r = 0; r < 4; r++) {
            float4 rv = *reinterpret_cast<const float4*>(&rows[which][r][c]); // b128 broadcast
            acc[r] += rv.x * wv.x + rv.y * wv.y + rv.z * wv.z + rv.w * wv.w;
        }
    }
    if (which == 0) {
        float bias = attn_b[o];
        #pragma unroll
        for (int r = 0; r < 4; r++)
            eq[(row0 + r) * Hn + o] = fast_exp2(C2 * (acc[r] + bias));
    } else {
        float4 ev;
        ev.x = fast_exp2(C2 * acc[0]); ev.y = fast_exp2(C2 * acc[1]);
        ev.z = fast_exp2(C2 * acc[2]); ev.w = fast_exp2(C2 * acc[3]);
        *reinterpret_cast<float4*>(&ekT[(size_t)(b * Hn + o) * Sn + t0]) = ev;
    }
}

// Kernel 2: partial logits with 4s x 4t register tiles.
// grid (16 s-tiles, Bn, 8 = 4 t-quarters * 2 h-halves), 256 threads.
// thread = (sg in 8, tc in 32): owns s0b+sg*4..+4 x t0..t0+4, loops 64 h.
// Per h-step: 1 ds_read_b128 (q, 4s) + 1 dwordx4 (ek, 4t) feed 16 rcp+32 fma.
__global__ __launch_bounds__(256) void score_kernel(
    const float* __restrict__ eq, const float* __restrict__ ekT,
    const float* __restrict__ v_w, float* __restrict__ pl)
{
    __shared__ float4 qs[8][64];     // [sg][h] = eq rows s0b+sg*4..+4 at h  (8 KB)
    __shared__ float  ws[64];

    const int b   = blockIdx.y;
    const int s0b = blockIdx.x * 32;
    const int tq  = blockIdx.z >> 1;
    const int hh  = blockIdx.z & 1;
    const int hb  = hh * 64;
    const int tid = threadIdx.x;
    const int tc  = tid & 31;
    const int sg  = tid >> 5;
    const int t0  = tq * 128 + tc * 4;

    // stage q transposed: qs[sg][h][sl] = eq[b][s0b+sg*4+sl][hb+h]
    for (int i = tid; i < 2048; i += 256) {
        int isg = i >> 8, sl = (i >> 6) & 3, h = i & 63;
        ((float*)&qs[isg][h])[sl] =
            eq[(size_t)(b * Sn + s0b + isg * 4 + sl) * Hn + hb + h];
    }
    if (tid < 64) ws[tid] = v_w[hb + tid];
    __syncthreads();

    const float* kb = ekT + ((size_t)b * Hn + hb) * Sn + t0;
    float4 A0 = {0,0,0,0}, A1 = {0,0,0,0}, A2 = {0,0,0,0}, A3 = {0,0,0,0};

    float4 cur = *reinterpret_cast<const float4*>(kb);
    #pragma unroll 4
    for (int h = 0; h < 63; h++) {
        float4 nxt = *reinterpret_cast<const float4*>(kb + (size_t)(h + 1) * Sn);
        float4 q4 = qs[sg][h];          // ds_read_b128, 2 broadcast groups/wave
        float  w  = ws[h];              // ds_read_b32 broadcast
        A0.x += w * fast_rcp(q4.x * cur.x + 1.f); A0.y += w * fast_rcp(q4.x * cur.y + 1.f);
        A0.z += w * fast_rcp(q4.x * cur.z + 1.f); A0.w += w * fast_rcp(q4.x * cur.w + 1.f);
        A1.x += w * fast_rcp(q4.y * cur.x + 1.f); A1.y += w * fast_rcp(q4.y * cur.y + 1.f);
        A1.z += w * fast_rcp(q4.y * cur.z + 1.f); A1.w += w * fast_rcp(q4.y * cur.w + 1.f);
        A2.x += w * fast_rcp(q4.z * cur.x + 1.f); A2.y += w * fast_rcp(q4.z * cur.y + 1.f);
        A2.z += w * fast_rcp(q4.z * cur.z + 1.f); A2.w += w * fast_rcp(q4.z * cur.w + 1.f);
        A3.x += w * fast_rcp(q4.w * cur.x + 1.f); A3.y += w * fast_rcp(q4.w * cur.y + 1.f);
        A3.z += w * fast_rcp(q4.w * cur.z + 1.f); A3.w += w * fast_rcp(q4.w * cur.w + 1.f);
        cur = nxt;
    }
    {   // h = 63 epilogue
        float4 q4 = qs[sg][63];
        float  w  = ws[63];
        A0.x += w * fast_rcp(q4.x * cur.x + 1.f); A0.y += w * fast_rcp(q4.x * cur.y + 1.f);
        A0.z += w * fast_rcp(q4.x * cur.z + 1.f); A0.w += w * fast_rcp(q4.x * cur.w + 1.f);
        A1.x += w * fast_rcp(q4.y * cur.x + 1.f); A1.y += w * fast_rcp(q4.y * cur.y + 1.f);
        A1.z += w * fast_rcp(q4.y * cur.z + 1.f); A1.w += w * fast_rcp(q4.y * cur.w + 1.f);
        A2.x += w * fast_rcp(q4.z * cur.x + 1.f); A2.y += w * fast_rcp(q4.z * cur.y + 1.f);
        A2.z += w * fast_rcp(q4.z * cur.z + 1.f); A2.w += w * fast_rcp(q4.z * cur.w + 1.f);
        A3.x += w * fast_rcp(q4.w * cur.x + 1.f); A3.y += w * fast_rcp(q4.w * cur.y + 1.f);
        A3.z += w * fast_rcp(q4.w * cur.z + 1.f); A3.w += w * fast_rcp(q4.w * cur.w + 1.f);
    }

    float* dst = pl + (((size_t)hh * Bn + b) * Sn + (s0b + sg * 4)) * Sn + t0;
    float4 O;
    O.x = -2.f * A0.x; O.y = -2.f * A0.y; O.z = -2.f * A0.z; O.w = -2.f * A0.w;
    *reinterpret_cast<float4*>(dst)           = O;
    O.x = -2.f * A1.x; O.y = -2.f * A1.y; O.z = -2.f * A1.z; O.w = -2.f * A1.w;
    *reinterpret_cast<float4*>(dst + Sn)      = O;
    O.x = -2.f * A2.x; O.y = -2.f * A2.y; O.z = -2.f * A2.z; O.w = -2.f * A2.w;
    *reinterpret_cast<float4*>(dst + 2 * Sn)  = O;
    O.x = -2.f * A3.x; O.y = -2.f * A3.y; O.z = -2.f * A3.z; O.w = -2.f * A3.w;
    *reinterpret_cast<float4*>(dst + 3 * Sn)  = O;
}

// Kernel 3: softmax (summing the 2 h-half strips) + PV.  512 threads, grid (Sn/ST, Bn).
__global__ __launch_bounds__(512) void softpv_kernel(
    const float* __restrict__ value, const float* __restrict__ pl,
    float* __restrict__ out, float* __restrict__ out_w)
{
    __shared__ float4 scT4[Sn];               // weights transposed  8 KB
    __shared__ float4 part4[16][ST][Hn / 4];  // PV partials        32 KB

    const int b   = blockIdx.y;
    const int s0  = blockIdx.x * ST;
    const int tid = threadIdx.x;
    const int wave = tid >> 6, lane = tid & 63;

    if (wave < ST) {
        const int sr = wave;
        const float* r0 = pl + ((size_t)(0 * Bn + b) * Sn + (s0 + sr)) * Sn;
        const float* r1 = pl + ((size_t)(1 * Bn + b) * Sn + (s0 + sr)) * Sn;
        float v[8]; float m = -1e30f;
        #pragma unroll
        for (int i = 0; i < 8; i++) {
            v[i] = r0[lane + i * 64] + r1[lane + i * 64];
            m = fmaxf(m, v[i]);
        }
        #pragma unroll
        for (int off = 32; off; off >>= 1) m = fmaxf(m, __shfl_xor(m, off, 64));
        float sum = 0.f;
        const float l2e = 1.4426950408889634f;
        #pragma unroll
        for (int i = 0; i < 8; i++) { v[i] = fast_exp2((v[i] - m) * l2e); sum += v[i]; }
        #pragma unroll
        for (int off = 32; off; off >>= 1) sum += __shfl_xor(sum, off, 64);
        float inv = 1.0f / sum;
        float* wrow_out = out_w + (size_t)(b * Sn + s0 + sr) * Sn;
        #pragma unroll
        for (int i = 0; i < 8; i++) {
            float wgt = v[i] * inv;
            wrow_out[lane + i * 64] = wgt;             // normalized weights out
            ((float*)&scT4[lane + i * 64])[sr] = wgt;  // transposed copy for PV
        }
    }
    __syncthreads();

    // PV: thread = (tg in 16, hq in 32); value read once per block
    {
        const int hq = tid & 31, tg = tid >> 5;
        const float* vb = value + ((size_t)b * Sn + tg * 32) * Hn + hq * 4;
        float4 A0 = {0,0,0,0}, A1 = {0,0,0,0}, A2 = {0,0,0,0}, A3 = {0,0,0,0};
        #pragma unroll 4
        for (int i = 0; i < 32; i++) {
            float4 v4 = *reinterpret_cast<const float4*>(vb + i * Hn);
            float4 w4 = scT4[tg * 32 + i];     // b128 broadcast
            A0.x += w4.x * v4.x; A0.y += w4.x * v4.y; A0.z += w4.x * v4.z; A0.w += w4.x * v4.w;
            A1.x += w4.y * v4.x; A1.y += w4.y * v4.y; A1.z += w4.y * v4.z; A1.w += w4.y * v4.w;
            A2.x += w4.z * v4.x; A2.y += w4.z * v4.y; A2.z += w4.z * v4.z; A2.w += w4.z * v4.w;
            A3.x += w4.w * v4.x; A3.y += w4.w * v4.y; A3.z += w4.w * v4.z; A3.w += w4.w * v4.w;
        }
        part4[tg][0][hq] = A0;
        part4[tg][1][hq] = A1;
        part4[tg][2][hq] = A2;
        part4[tg][3][hq] = A3;
    }
    __syncthreads();
    {
        const int sg = tid >> 7, h = tid & 127;
        float r = 0.f;
        #pragma unroll
        for (int tg = 0; tg < 16; tg++)
            r += ((const float*)&part4[tg][sg][h >> 2])[h & 3];
        out[(b * Sn + s0 + sg) * Hn + h] = r;
    }
}

extern "C" void kernel_launch(void* const* d_in, const int* in_sizes, int n_in,
                              void* d_out, int out_size, void* d_ws, size_t ws_size,
                              hipStream_t stream) {
    const float* query  = (const float*)d_in[0];
    const float* key    = (const float*)d_in[1];
    const float* value  = (const float*)d_in[2];
    const float* attn_W = (const float*)d_in[3];
    const float* attn_b = (const float*)d_in[4];
    const float* v_w    = (const float*)d_in[5];

    float* out   = (float*)d_out;            // (B,S,H) then (B,S,S), both f32
    float* out_w = out + Bn * Sn * Hn;

    float* eq  = (float*)d_ws;               // B*S*H floats = 1 MB
    float* ekT = eq + Bn * Sn * Hn;          // B*H*S floats = 1 MB
    float* pl  = ekT + Bn * Hn * Sn;         // 2*B*S*S floats = 8 MB

    proj_kernel<<<Bn * Sn / 4, 256, 0, stream>>>(query, key, attn_W, attn_b, eq, ekT);
    score_kernel<<<dim3(16, Bn, 8), 256, 0, stream>>>(eq, ekT, v_w, pl);
    softpv_kernel<<<dim3(Sn / ST, Bn), 512, 0, stream>>>(value, pl, out, out_w);
}

// Round 9
// 45.294 us; speedup vs baseline: 1.0405x; 1.0405x over previous
//
#include <hip/hip_runtime.h>

#define Bn 4
#define Sn 512
#define Hn 128
#define ST 4   // s-rows per softpv block

__device__ __forceinline__ float fast_exp2(float x) { return __builtin_amdgcn_exp2f(x); }
__device__ __forceinline__ float fast_rcp(float x)  { return __builtin_amdgcn_rcpf(x); }

#define C2 2.8853900817779268f   // 2*log2(e)

// Kernel 1: eq[b][s][h] = exp2(C2*(q@Wq^T + bias)) ; ekT[b][h][t] = exp2(C2*(k@Wk^T))
__global__ __launch_bounds__(256) void proj_kernel(
    const float* __restrict__ query, const float* __restrict__ key,
    const float* __restrict__ attn_W, const float* __restrict__ attn_b,
    float* __restrict__ eq, float* __restrict__ ekT)
{
    __shared__ float rows[2][4][Hn];       // 4 KB
    const int row0 = blockIdx.x * 4;       // global (b*S+s) row
    const int b    = row0 / Sn;
    const int t0   = row0 % Sn;            // multiple of 4
    const int tid  = threadIdx.x;

    {   // 2*4*128 floats = 256 float4, one per thread
        int src = tid >> 7, r = (tid >> 5) & 3, c4 = tid & 31;
        ((float4*)rows)[tid] =
            reinterpret_cast<const float4*>(src ? key : query)[(row0 + r) * 32 + c4];
    }
    __syncthreads();

    const int o     = tid & 127;
    const int which = tid >> 7;            // 0 = q-proj, 1 = k-proj (wave-uniform)
    float acc[4] = {0,0,0,0};
    const float* wrow = attn_W + o * (2 * Hn) + which * Hn;
    for (int c = 0; c < Hn; c += 4) {
        float4 wv = *reinterpret_cast<const float4*>(wrow + c);
        #pragma unroll
        for (int r = 0; r < 4; r++) {
            float4 rv = *reinterpret_cast<const float4*>(&rows[which][r][c]); // b128 broadcast
            acc[r] += rv.x * wv.x + rv.y * wv.y + rv.z * wv.z + rv.w * wv.w;
        }
    }
    if (which == 0) {
        float bias = attn_b[o];
        #pragma unroll
        for (int r = 0; r < 4; r++)
            eq[(row0 + r) * Hn + o] = fast_exp2(C2 * (acc[r] + bias));
    } else {
        float4 ev;
        ev.x = fast_exp2(C2 * acc[0]); ev.y = fast_exp2(C2 * acc[1]);
        ev.z = fast_exp2(C2 * acc[2]); ev.w = fast_exp2(C2 * acc[3]);
        *reinterpret_cast<float4*>(&ekT[(size_t)(b * Hn + o) * Sn + t0]) = ev;
    }
}

// Kernel 2: partial logits, 2s x 4t x 64h register tiles.
// grid (32 s-tiles, Bn, 4 t-quarters * 2 h-halves) = 1024 blocks x 256 threads
// -> 4 blocks/CU, 4 waves/SIMD. thread = (sg in 8, tc in 32).
// Per h-step: 1 ds_read_b64 (q pair) + 1 ds_read_b32 (w) + 1 dwordx4 (ek)
// feed 8 rcp + 16 fma.  pl[hh][b][s][t] = sum_{h in half} (-2 v_w[h])*sigma
__global__ __launch_bounds__(256) void score_kernel(
    const float* __restrict__ eq, const float* __restrict__ ekT,
    const float* __restrict__ v_w, float* __restrict__ pl)
{
    __shared__ float2 qs2[8][64];    // [sg][h] = eq rows (s0b+sg*2, +1) at hb+h  (4 KB)
    __shared__ float  ws[64];        // -2 * v_w[hb+h]

    const int b   = blockIdx.y;
    const int s0b = blockIdx.x * 16;
    const int tq  = blockIdx.z >> 1;
    const int hh  = blockIdx.z & 1;
    const int hb  = hh * 64;
    const int tid = threadIdx.x;
    const int tc  = tid & 31;
    const int sg  = tid >> 5;        // 0..7 (wave-uniform per half-wave)
    const int t0  = tq * 128 + tc * 4;

    // stage q transposed into pairs: qs2[isg][h][sl] = eq[b][s0b+isg*2+sl][hb+h]
    for (int i = tid; i < 1024; i += 256) {
        int isg = i >> 7, sl = (i >> 6) & 1, h = i & 63;
        ((float*)&qs2[isg][h])[sl] =
            eq[(size_t)(b * Sn + s0b + isg * 2 + sl) * Hn + hb + h];
    }
    if (tid < 64) ws[tid] = -2.0f * v_w[hb + tid];
    __syncthreads();

    const float* kb = ekT + ((size_t)b * Hn + hb) * Sn + t0;
    float4 A0 = {0,0,0,0}, A1 = {0,0,0,0};

    float4 cur = *reinterpret_cast<const float4*>(kb);
    #pragma unroll 8
    for (int h = 0; h < 64; h++) {
        // wrap-around prefetch (h=63 re-reads line 0 of the same tile: safe, unused)
        float4 nxt = *reinterpret_cast<const float4*>(kb + (size_t)((h + 1) & 63) * Sn);
        float2 q2 = qs2[sg][h];      // ds_read_b64 broadcast
        float  w  = ws[h];           // ds_read_b32 broadcast
        A0.x += w * fast_rcp(q2.x * cur.x + 1.f);
        A0.y += w * fast_rcp(q2.x * cur.y + 1.f);
        A0.z += w * fast_rcp(q2.x * cur.z + 1.f);
        A0.w += w * fast_rcp(q2.x * cur.w + 1.f);
        A1.x += w * fast_rcp(q2.y * cur.x + 1.f);
        A1.y += w * fast_rcp(q2.y * cur.y + 1.f);
        A1.z += w * fast_rcp(q2.y * cur.z + 1.f);
        A1.w += w * fast_rcp(q2.y * cur.w + 1.f);
        cur = nxt;
    }

    float* dst = pl + (((size_t)hh * Bn + b) * Sn + (s0b + sg * 2)) * Sn + t0;
    *reinterpret_cast<float4*>(dst)      = A0;
    *reinterpret_cast<float4*>(dst + Sn) = A1;
}

// Kernel 3: softmax (summing the 2 h-half strips) + PV.  512 threads, grid (Sn/ST, Bn).
__global__ __launch_bounds__(512) void softpv_kernel(
    const float* __restrict__ value, const float* __restrict__ pl,
    float* __restrict__ out, float* __restrict__ out_w)
{
    __shared__ float4 scT4[Sn];               // weights transposed  8 KB
    __shared__ float4 part4[16][ST][Hn / 4];  // PV partials        32 KB

    const int b   = blockIdx.y;
    const int s0  = blockIdx.x * ST;
    const int tid = threadIdx.x;
    const int wave = tid >> 6, lane = tid & 63;

    if (wave < ST) {
        const int sr = wave;
        const float* r0 = pl + ((size_t)(0 * Bn + b) * Sn + (s0 + sr)) * Sn;
        const float* r1 = pl + ((size_t)(1 * Bn + b) * Sn + (s0 + sr)) * Sn;
        float v[8]; float m = -1e30f;
        #pragma unroll
        for (int i = 0; i < 8; i++) {
            v[i] = r0[lane + i * 64] + r1[lane + i * 64];
            m = fmaxf(m, v[i]);
        }
        #pragma unroll
        for (int off = 32; off; off >>= 1) m = fmaxf(m, __shfl_xor(m, off, 64));
        float sum = 0.f;
        const float l2e = 1.4426950408889634f;
        #pragma unroll
        for (int i = 0; i < 8; i++) { v[i] = fast_exp2((v[i] - m) * l2e); sum += v[i]; }
        #pragma unroll
        for (int off = 32; off; off >>= 1) sum += __shfl_xor(sum, off, 64);
        float inv = 1.0f / sum;
        float* wrow_out = out_w + (size_t)(b * Sn + s0 + sr) * Sn;
        #pragma unroll
        for (int i = 0; i < 8; i++) {
            float wgt = v[i] * inv;
            wrow_out[lane + i * 64] = wgt;             // normalized weights out
            ((float*)&scT4[lane + i * 64])[sr] = wgt;  // transposed copy for PV
        }
    }
    __syncthreads();

    // PV: thread = (tg in 16, hq in 32); value read once per block
    {
        const int hq = tid & 31, tg = tid >> 5;
        const float* vb = value + ((size_t)b * Sn + tg * 32) * Hn + hq * 4;
        float4 A0 = {0,0,0,0}, A1 = {0,0,0,0}, A2 = {0,0,0,0}, A3 = {0,0,0,0};
        #pragma unroll 4
        for (int i = 0; i < 32; i++) {
            float4 v4 = *reinterpret_cast<const float4*>(vb + i * Hn);
            float4 w4 = scT4[tg * 32 + i];     // b128 broadcast
            A0.x += w4.x * v4.x; A0.y += w4.x * v4.y; A0.z += w4.x * v4.z; A0.w += w4.x * v4.w;
            A1.x += w4.y * v4.x; A1.y += w4.y * v4.y; A1.z += w4.y * v4.z; A1.w += w4.y * v4.w;
            A2.x += w4.z * v4.x; A2.y += w4.z * v4.y; A2.z += w4.z * v4.z; A2.w += w4.z * v4.w;
            A3.x += w4.w * v4.x; A3.y += w4.w * v4.y; A3.z += w4.w * v4.z; A3.w += w4.w * v4.w;
        }
        part4[tg][0][hq] = A0;
        part4[tg][1][hq] = A1;
        part4[tg][2][hq] = A2;
        part4[tg][3][hq] = A3;
    }
    __syncthreads();
    {
        const int sg = tid >> 7, h = tid & 127;
        float r = 0.f;
        #pragma unroll
        for (int tg = 0; tg < 16; tg++)
            r += ((const float*)&part4[tg][sg][h >> 2])[h & 3];
        out[(b * Sn + s0 + sg) * Hn + h] = r;
    }
}

extern "C" void kernel_launch(void* const* d_in, const int* in_sizes, int n_in,
                              void* d_out, int out_size, void* d_ws, size_t ws_size,
                              hipStream_t stream) {
    const float* query  = (const float*)d_in[0];
    const float* key    = (const float*)d_in[1];
    const float* value  = (const float*)d_in[2];
    const float* attn_W = (const float*)d_in[3];
    const float* attn_b = (const float*)d_in[4];
    const float* v_w    = (const float*)d_in[5];

    float* out   = (float*)d_out;            // (B,S,H) then (B,S,S), both f32
    float* out_w = out + Bn * Sn * Hn;

    float* eq  = (float*)d_ws;               // B*S*H floats = 1 MB
    float* ekT = eq + Bn * Sn * Hn;          // B*H*S floats = 1 MB
    float* pl  = ekT + Bn * Hn * Sn;         // 2*B*S*S floats = 8 MB

    proj_kernel<<<Bn * Sn / 4, 256, 0, stream>>>(query, key, attn_W, attn_b, eq, ekT);
    score_kernel<<<dim3(32, Bn, 8), 256, 0, stream>>>(eq, ekT, v_w, pl);
    softpv_kernel<<<dim3(Sn / ST, Bn), 512, 0, stream>>>(value, pl, out, out_w);
}